// Round 4
// baseline (100.341 us; speedup 1.0000x reference)
//
#include <hip/hip_runtime.h>
#include <hip/hip_bf16.h>

// MultiHeadLinearAttention2D on MI355X (gfx950), bf16-MFMA implementation.
// B=16, C_in=C_out=256, H=W=64 (M=4096), heads=8, dh=32, scale=1/sqrt(32).
//
// Round-4: hoist the fp32->bf16 transpose out of the hot kernels.
//  - xcvt streams x once into pre-swizzled bf16 tile images (the exact 32KB
//    LDS image k_kv/k_q want), pure BW kernel.
//  - k_kv / k_q stage tiles with global_load_lds (16B, async, no VGPR
//    round-trip, no ds_write, no convert VALU), 2-phase issue-ahead pipeline.
//  - k_kv restored to acc[4][4] (one weight frag feeds 4 MFMAs).

typedef __attribute__((ext_vector_type(8))) short bf16x8;
typedef __attribute__((ext_vector_type(4))) float f32x4;
typedef __attribute__((ext_vector_type(4))) unsigned int u32x4;
typedef __attribute__((ext_vector_type(4))) float float4v;

#define DEVI static __device__ __forceinline__

DEVI unsigned short f2bf(float f){
  unsigned int u = __builtin_bit_cast(unsigned int, f);
  u = (u + 0x7fffu + ((u >> 16) & 1u)) >> 16;   // RNE truncate to bf16
  return (unsigned short)u;
}
DEVI unsigned int pk2(float a, float b){
  return (unsigned int)f2bf(a) | ((unsigned int)f2bf(b) << 16);
}
DEVI float feat(float p){   // (elu(p)+1) * 1/sqrt(32)
  return (p > 0.f ? p + 1.f : __expf(p)) * 0.17677669529663687f;
}

DEVI f32x4 mfma16(u32x4 a, u32x4 b, f32x4 c){
  return __builtin_amdgcn_mfma_f32_16x16x32_bf16(
      __builtin_bit_cast(bf16x8, a), __builtin_bit_cast(bf16x8, b), c, 0, 0, 0);
}

// byte-XOR swizzle (G4) for 512B rows of the x^T tile image
DEVI int swz8(int m){ return ((m ^ (m >> 3)) & 7) << 4; }

// async global->LDS, 16B per lane; LDS base must be wave-uniform
typedef __attribute__((address_space(3))) unsigned int as3_u32;
typedef __attribute__((address_space(1))) const unsigned int as1_u32;
DEVI void gload16(const void* g, void* l){
  __builtin_amdgcn_global_load_lds((as1_u32*)g, (as3_u32*)l, 16, 0, 0);
}
// stage one 32KB pre-swizzled tile image (global -> LDS), async
DEVI void stage_tile(const char* src, void* buf, int w, int lane){
  #pragma unroll
  for (int i = 0; i < 4; ++i){
    int ub = w * 1024 + i * 8192;               // wave-uniform LDS base
    gload16(src + ub + lane * 16, (char*)buf + ub);
  }
}

// --- fp32 x-tile [256 c][64 m] -> registers -> swizzled bf16 image ----------
DEVI void stage_load(const float* __restrict__ xb, int m0, int tid, float4v* r){
  #pragma unroll
  for (int it = 0; it < 2; ++it){
    int cq = (tid >> 4) + it * 32;     // 0..63 -> c0 = 4*cq
    int mq = tid & 15;                 // 0..15 -> ml0 = 4*mq
    const float* p = xb + (size_t)(cq * 4) * 4096 + m0 + mq * 4;
    r[it*4+0] = *(const float4v*)(p);
    r[it*4+1] = *(const float4v*)(p + 4096);
    r[it*4+2] = *(const float4v*)(p + 8192);
    r[it*4+3] = *(const float4v*)(p + 12288);
  }
}
DEVI void stage_write(unsigned short* xT, int tid, const float4v* r){
  #pragma unroll
  for (int it = 0; it < 2; ++it){
    int cq = (tid >> 4) + it * 32;
    int mq = tid & 15;
    int c0 = cq * 4, ml0 = mq * 4;
    #pragma unroll
    for (int j = 0; j < 4; ++j){
      int m = ml0 + j;
      unsigned int lo = pk2(r[it*4+0][j], r[it*4+1][j]);
      unsigned int hi = pk2(r[it*4+2][j], r[it*4+3][j]);
      int off = m * 512 + ((c0 * 2) ^ swz8(m));
      unsigned long long v = (unsigned long long)lo | ((unsigned long long)hi << 32);
      *(unsigned long long*)((char*)xT + off) = v;
    }
  }
}

// ---------------- kernel 0: weight fp32 -> bf16 ----------------
__global__ void wconv(const float* __restrict__ wq, const float* __restrict__ wk,
                      const float* __restrict__ wv,
                      unsigned short* __restrict__ wkv, unsigned short* __restrict__ wqb){
  int i = blockIdx.x * 256 + threadIdx.x;
  if (i < 65536){
    wkv[i]         = f2bf(wk[i]);   // rows 0..255   = Wk
    wkv[65536 + i] = f2bf(wv[i]);   // rows 256..511 = Wv
    wqb[i]         = f2bf(wq[i]);
  }
}

// ---------------- kernel 0b: x -> pre-swizzled bf16 tile images -------------
// ximg: [b][64 tiles][16384 ushort] ; tile = x^T [64 m][256 c] swizzled image
__global__ void __launch_bounds__(512) xcvt(const float* __restrict__ x,
                                            unsigned short* __restrict__ ximg){
  __shared__ __align__(16) unsigned short xT[16384];
  const int tid = threadIdx.x;
  const int ch = blockIdx.x, b = blockIdx.y;
  const float* xb = x + (size_t)b * (256 * 4096);
  for (int sub = 0; sub < 2; ++sub){
    int m0 = ch * 128 + sub * 64;
    float4v rs[8];
    stage_load(xb, m0, tid, rs);
    if (sub) __syncthreads();          // previous tile's dump finished
    stage_write(xT, tid, rs);
    __syncthreads();
    unsigned short* dst = ximg + ((size_t)b * 64 + (m0 >> 6)) * 16384;
    #pragma unroll
    for (int i = 0; i < 4; ++i){
      u32x4 v = *(const u32x4*)((const char*)xT + tid * 16 + i * 8192);
      *(u32x4*)((char*)dst + tid * 16 + i * 8192) = v;
    }
  }
}

// --- one 64-m subtile: K/V projection + fold into KV/ksum accumulators ------
DEVI void compute_sub(const unsigned short* __restrict__ xT,
                      const unsigned short* __restrict__ wkv,
                      int w, int l15, int hi,
                      f32x4 (&kvacc)[2][2], f32x4 (&ksacc)[2], u32x4 ones){
  f32x4 acc[4][4];                         // [nt m-tile][ot: 0,1=K, 2,3=V]
  #pragma unroll
  for (int a1 = 0; a1 < 4; ++a1)
    #pragma unroll
    for (int a2 = 0; a2 < 4; ++a2) acc[a1][a2] = f32x4{0.f,0.f,0.f,0.f};

  for (int kk = 0; kk < 8; ++kk){
    u32x4 xf[4];
    #pragma unroll
    for (int nt = 0; nt < 4; ++nt){
      int m = nt * 16 + l15;
      xf[nt] = *(const u32x4*)((const char*)xT + m * 512 + ((kk * 64 + hi * 16) ^ swz8(m)));
    }
    #pragma unroll
    for (int ot = 0; ot < 4; ++ot){
      int row = (ot < 2) ? (w * 32 + ot * 16 + l15)
                         : (256 + w * 32 + (ot - 2) * 16 + l15);
      u32x4 wf = *(const u32x4*)(wkv + (size_t)row * 256 + kk * 32 + hi * 8);
      #pragma unroll
      for (int nt = 0; nt < 4; ++nt) acc[nt][ot] = mfma16(xf[nt], wf, acc[nt][ot]);
    }
  }
  // lane holds c = l15 (per o-tile), 8 m-values; pack bf16 frags in-register.
  #pragma unroll
  for (int g = 0; g < 2; ++g){
    u32x4 kf[2], vf[2];
    #pragma unroll
    for (int t2 = 0; t2 < 2; ++t2){
      kf[t2][0] = pk2(feat(acc[2*g][t2][0]),   feat(acc[2*g][t2][1]));
      kf[t2][1] = pk2(feat(acc[2*g][t2][2]),   feat(acc[2*g][t2][3]));
      kf[t2][2] = pk2(feat(acc[2*g+1][t2][0]), feat(acc[2*g+1][t2][1]));
      kf[t2][3] = pk2(feat(acc[2*g+1][t2][2]), feat(acc[2*g+1][t2][3]));
      vf[t2][0] = pk2(acc[2*g][t2+2][0],   acc[2*g][t2+2][1]);
      vf[t2][1] = pk2(acc[2*g][t2+2][2],   acc[2*g][t2+2][3]);
      vf[t2][2] = pk2(acc[2*g+1][t2+2][0], acc[2*g+1][t2+2][1]);
      vf[t2][3] = pk2(acc[2*g+1][t2+2][2], acc[2*g+1][t2+2][3]);
    }
    #pragma unroll
    for (int ct = 0; ct < 2; ++ct){
      #pragma unroll
      for (int dt = 0; dt < 2; ++dt)
        kvacc[ct][dt] = mfma16(kf[ct], vf[dt], kvacc[ct][dt]);
      ksacc[ct] = mfma16(kf[ct], ones, ksacc[ct]);
    }
  }
}

// ---------------- kernel 1: K/V projection + per-chunk KV & ksum partials ----
// grid (32 chunks, 16 batches), 512 threads = 8 waves = 8 heads; 2 subtiles.
__global__ void __launch_bounds__(512) k_kv(const unsigned short* __restrict__ ximg,
        const unsigned short* __restrict__ wkv,
        float* __restrict__ kvp, float* __restrict__ ksp){
  __shared__ __align__(16) unsigned short xT[2][16384];   // 64KB double-buffer
  const int tid = threadIdx.x, lane = tid & 63, w = tid >> 6;
  const int l15 = lane & 15, hi = lane >> 4;
  const int ch = blockIdx.x, b = blockIdx.y;
  const char* src = (const char*)(ximg + ((size_t)b * 64 + ch * 2) * 16384);

  f32x4 kvacc[2][2];
  f32x4 ksacc[2];
  #pragma unroll
  for (int i = 0; i < 2; ++i){
    ksacc[i] = f32x4{0.f,0.f,0.f,0.f};
    #pragma unroll
    for (int j = 0; j < 2; ++j) kvacc[i][j] = f32x4{0.f,0.f,0.f,0.f};
  }
  u32x4 ones = {0u,0u,0u,0u};               // B-frag: column d=0 all-ones -> ksum
  if (l15 == 0){ ones[0] = ones[1] = ones[2] = ones[3] = 0x3f803f80u; }

  stage_tile(src, xT[0], w, lane);
  __syncthreads();                                   // t0 ready
  stage_tile(src + 32768, xT[1], w, lane);           // issue t1 async
  compute_sub(xT[0], wkv, w, l15, hi, kvacc, ksacc, ones);
  __syncthreads();                                   // t1 drained
  compute_sub(xT[1], wkv, w, l15, hi, kvacc, ksacc, ones);

  // partial stores: kvp [b][32 ch][8 h][32 c][32 d], ksp [b][32 ch][8 h][32 c]
  size_t base = (((size_t)b * 32 + ch) * 8 + w) * 1024;
  #pragma unroll
  for (int ct = 0; ct < 2; ++ct){
    #pragma unroll
    for (int dt = 0; dt < 2; ++dt){
      #pragma unroll
      for (int r = 0; r < 4; ++r){
        int c = ct * 16 + hi * 4 + r, d = dt * 16 + l15;
        kvp[base + c * 32 + d] = kvacc[ct][dt][r];
      }
    }
  }
  if (l15 == 0){
    size_t kb = (((size_t)b * 32 + ch) * 8 + w) * 32;
    #pragma unroll
    for (int ct = 0; ct < 2; ++ct)
      #pragma unroll
      for (int r = 0; r < 4; ++r) ksp[kb + ct * 16 + hi * 4 + r] = ksacc[ct][r];
  }
}

// ---------------- kernel 2: reduce partials -> KV^T bf16 [b][h][d][pos(c)], ksum bf16
// slot permutation matching k_q's in-register q frag: pos(c) = ((c>>2)&3)*8 + (c>>4)*4 + (c&3)
__global__ void k_red(const float* __restrict__ kvp, const float* __restrict__ ksp,
                      unsigned short* __restrict__ kvt, unsigned short* __restrict__ ksb){
  int t = blockIdx.x * 256 + threadIdx.x;   // 32768 threads: (b,h,c,dq)
  int dq = t & 7;            // d-quad
  int c  = (t >> 3) & 31;
  int h  = (t >> 8) & 7;
  int b  = t >> 11;
  float4v s = {0.f,0.f,0.f,0.f};
  for (int c2 = 0; c2 < 32; ++c2){
    const float* p = kvp + ((((size_t)b * 32 + c2) * 8 + h) * 1024) + c * 32 + dq * 4;
    float4v r = *(const float4v*)p;
    s.x += r.x; s.y += r.y; s.z += r.z; s.w += r.w;
  }
  int pos = ((c >> 2) & 3) * 8 + ((c >> 4) << 2) + (c & 3);
  unsigned short* q = kvt + ((size_t)b * 8 + h) * 1024;
  q[(dq * 4 + 0) * 32 + pos] = f2bf(s.x);
  q[(dq * 4 + 1) * 32 + pos] = f2bf(s.y);
  q[(dq * 4 + 2) * 32 + pos] = f2bf(s.z);
  q[(dq * 4 + 3) * 32 + pos] = f2bf(s.w);
  if (dq == 0){
    float ks = 0.f;
    for (int c2 = 0; c2 < 32; ++c2)
      ks += ksp[(((size_t)b * 32 + c2) * 8 + h) * 32 + c];
    ksb[((size_t)b * 8 + h) * 32 + pos] = f2bf(ks);
  }
}

// --- one 64-m subtile of k_q: Q projection + out = KV^T q / denom -----------
DEVI void q_sub(const unsigned short* __restrict__ xT,
                const unsigned short* __restrict__ wqb,
                u32x4 afkv0, u32x4 afkv1, u32x4 afd,
                int w, int l15, int hi, float* __restrict__ ob){
  f32x4 qa[2][4];                           // [ot = c-tile][nt = m-tile]
  #pragma unroll
  for (int a1 = 0; a1 < 2; ++a1)
    #pragma unroll
    for (int a2 = 0; a2 < 4; ++a2) qa[a1][a2] = f32x4{0.f,0.f,0.f,0.f};

  for (int kk = 0; kk < 8; ++kk){
    u32x4 xf[4];
    #pragma unroll
    for (int nt = 0; nt < 4; ++nt){
      int m = nt * 16 + l15;
      xf[nt] = *(const u32x4*)((const char*)xT + m * 512 + ((kk * 64 + hi * 16) ^ swz8(m)));
    }
    #pragma unroll
    for (int ot = 0; ot < 2; ++ot){
      int row = w * 32 + ot * 16 + l15;     // head w channels
      u32x4 wf = *(const u32x4*)(wqb + (size_t)row * 256 + kk * 32 + hi * 8);
      #pragma unroll
      for (int nt = 0; nt < 4; ++nt) qa[ot][nt] = mfma16(wf, xf[nt], qa[ot][nt]);
    }
  }

  #pragma unroll
  for (int nt = 0; nt < 4; ++nt){
    // q B-frag in-register: lane l15 = m, slots = c (ot0 r0..3, ot1 r0..3)
    u32x4 bq;
    bq[0] = pk2(feat(qa[0][nt][0]), feat(qa[0][nt][1]));
    bq[1] = pk2(feat(qa[0][nt][2]), feat(qa[0][nt][3]));
    bq[2] = pk2(feat(qa[1][nt][0]), feat(qa[1][nt][1]));
    bq[3] = pk2(feat(qa[1][nt][2]), feat(qa[1][nt][3]));

    f32x4 o0 = {0.f,0.f,0.f,0.f}, o1 = {0.f,0.f,0.f,0.f}, dn = {0.f,0.f,0.f,0.f};
    o0 = mfma16(afkv0, bq, o0);
    o1 = mfma16(afkv1, bq, o1);
    dn = mfma16(afd, bq, dn);
    float dv = __shfl(dn[0], l15, 64);       // lanes hi==0 hold denom[m] in reg0
    float inv = 1.0f / fmaxf(dv, 1e-6f);
    #pragma unroll
    for (int r = 0; r < 4; ++r){
      ob[(size_t)(hi * 4 + r) * 4096 + nt * 16 + l15]      = o0[r] * inv;
      ob[(size_t)(16 + hi * 4 + r) * 4096 + nt * 16 + l15] = o1[r] * inv;
    }
  }
}

// ---------------- kernel 3: Q projection + apply KV -------------------------
// grid (32 chunks, 16 batches), 512 threads = 8 waves = 8 heads; 2 subtiles.
__global__ void __launch_bounds__(512) k_q(const unsigned short* __restrict__ ximg,
        const unsigned short* __restrict__ wqb,
        const unsigned short* __restrict__ kvt,
        const unsigned short* __restrict__ ksb,
        float* __restrict__ out){
  __shared__ __align__(16) unsigned short xT[2][16384];   // 64KB double-buffer
  const int tid = threadIdx.x, lane = tid & 63, w = tid >> 6;
  const int l15 = lane & 15, hi = lane >> 4;
  const int ch = blockIdx.x, b = blockIdx.y;
  const char* src = (const char*)(ximg + ((size_t)b * 64 + ch * 2) * 16384);

  // KV^T / ksum frags (slot-permuted storage from k_red matches q packing)
  size_t kvbase = ((size_t)b * 8 + w) * 1024;
  u32x4 afkv0 = *(const u32x4*)(kvt + kvbase + (size_t)l15 * 32 + hi * 8);        // d = l15
  u32x4 afkv1 = *(const u32x4*)(kvt + kvbase + (size_t)(16 + l15) * 32 + hi * 8); // d = 16+l15
  u32x4 afd = {0u,0u,0u,0u};                 // row0 = ksum -> D[0][m] = denom
  if (l15 == 0) afd = *(const u32x4*)(ksb + ((size_t)b * 8 + w) * 32 + hi * 8);

  stage_tile(src, xT[0], w, lane);
  __syncthreads();                                   // t0 ready
  stage_tile(src + 32768, xT[1], w, lane);           // issue t1 async

  float* ob = out + ((size_t)b * 256 + w * 32) * 4096 + ch * 128;
  q_sub(xT[0], wqb, afkv0, afkv1, afd, w, l15, hi, ob);
  __syncthreads();                                   // t1 drained
  q_sub(xT[1], wqb, afkv0, afkv1, afd, w, l15, hi, ob + 64);
}

extern "C" void kernel_launch(void* const* d_in, const int* in_sizes, int n_in,
                              void* d_out, int out_size, void* d_ws, size_t ws_size,
                              hipStream_t stream) {
  const float* x  = (const float*)d_in[0];
  const float* wq = (const float*)d_in[1];
  const float* wk = (const float*)d_in[2];
  const float* wv = (const float*)d_in[3];
  float* out = (float*)d_out;
  char* ws = (char*)d_ws;

  // ws layout (bytes): total ~49.5 MB
  unsigned short* wkv  = (unsigned short*)(ws);                  // 262144
  unsigned short* wqb  = (unsigned short*)(ws + 262144);         // 131072
  unsigned short* kvt  = (unsigned short*)(ws + 393216);         // 262144
  unsigned short* ksb  = (unsigned short*)(ws + 655360);         // 8192
  float* kvp = (float*)(ws + 1048576);                           // 16777216
  float* ksp = (float*)(ws + 17825792);                          // 524288
  unsigned short* ximg = (unsigned short*)(ws + 18350080);       // 33554432

  hipLaunchKernelGGL(wconv, dim3(256), dim3(256), 0, stream, wq, wk, wv, wkv, wqb);
  hipLaunchKernelGGL(xcvt,  dim3(32, 16), dim3(512), 0, stream, x, ximg);
  hipLaunchKernelGGL(k_kv,  dim3(32, 16), dim3(512), 0, stream, ximg, wkv, kvp, ksp);
  hipLaunchKernelGGL(k_red, dim3(128), dim3(256), 0, stream, kvp, ksp, kvt, ksb);
  hipLaunchKernelGGL(k_q,   dim3(32, 16), dim3(512), 0, stream, ximg, wqb, kvt, ksb, out);
}

// Round 5
// 85.744 us; speedup vs baseline: 1.1702x; 1.1702x over previous
//
#include <hip/hip_runtime.h>
#include <hip/hip_bf16.h>

// MultiHeadLinearAttention2D on MI355X (gfx950), bf16-MFMA implementation.
// B=16, C_in=C_out=256, H=W=64 (M=4096), heads=8, dh=32, scale=1/sqrt(32).
//
// Round-5: weights pre-packed in FRAGMENT ORDER ([h][ot][kk][lane]*16B) so the
// hot-loop weight load is frag_base + lane*16 = one coalesced 1KB L2 load,
// instead of a 64-way row-gather (R4's hidden ~30us stall in k_kv/k_q).
// Everything else unchanged from round 4.

typedef __attribute__((ext_vector_type(8))) short bf16x8;
typedef __attribute__((ext_vector_type(4))) float f32x4;
typedef __attribute__((ext_vector_type(4))) unsigned int u32x4;
typedef __attribute__((ext_vector_type(4))) float float4v;

#define DEVI static __device__ __forceinline__

DEVI unsigned short f2bf(float f){
  unsigned int u = __builtin_bit_cast(unsigned int, f);
  u = (u + 0x7fffu + ((u >> 16) & 1u)) >> 16;   // RNE truncate to bf16
  return (unsigned short)u;
}
DEVI unsigned int pk2(float a, float b){
  return (unsigned int)f2bf(a) | ((unsigned int)f2bf(b) << 16);
}
DEVI float feat(float p){   // (elu(p)+1) * 1/sqrt(32)
  return (p > 0.f ? p + 1.f : __expf(p)) * 0.17677669529663687f;
}

DEVI f32x4 mfma16(u32x4 a, u32x4 b, f32x4 c){
  return __builtin_amdgcn_mfma_f32_16x16x32_bf16(
      __builtin_bit_cast(bf16x8, a), __builtin_bit_cast(bf16x8, b), c, 0, 0, 0);
}

// byte-XOR swizzle (G4) for 512B rows of the x^T tile image
DEVI int swz8(int m){ return ((m ^ (m >> 3)) & 7) << 4; }

// async global->LDS, 16B per lane; LDS base must be wave-uniform
typedef __attribute__((address_space(3))) unsigned int as3_u32;
typedef __attribute__((address_space(1))) const unsigned int as1_u32;
DEVI void gload16(const void* g, void* l){
  __builtin_amdgcn_global_load_lds((as1_u32*)g, (as3_u32*)l, 16, 0, 0);
}
// stage one 32KB pre-swizzled tile image (global -> LDS), async
DEVI void stage_tile(const char* src, void* buf, int w, int lane){
  #pragma unroll
  for (int i = 0; i < 4; ++i){
    int ub = w * 1024 + i * 8192;               // wave-uniform LDS base
    gload16(src + ub + lane * 16, (char*)buf + ub);
  }
}

// --- fp32 x-tile [256 c][64 m] -> registers -> swizzled bf16 image ----------
DEVI void stage_load(const float* __restrict__ xb, int m0, int tid, float4v* r){
  #pragma unroll
  for (int it = 0; it < 2; ++it){
    int cq = (tid >> 4) + it * 32;     // 0..63 -> c0 = 4*cq
    int mq = tid & 15;                 // 0..15 -> ml0 = 4*mq
    const float* p = xb + (size_t)(cq * 4) * 4096 + m0 + mq * 4;
    r[it*4+0] = *(const float4v*)(p);
    r[it*4+1] = *(const float4v*)(p + 4096);
    r[it*4+2] = *(const float4v*)(p + 8192);
    r[it*4+3] = *(const float4v*)(p + 12288);
  }
}
DEVI void stage_write(unsigned short* xT, int tid, const float4v* r){
  #pragma unroll
  for (int it = 0; it < 2; ++it){
    int cq = (tid >> 4) + it * 32;
    int mq = tid & 15;
    int c0 = cq * 4, ml0 = mq * 4;
    #pragma unroll
    for (int j = 0; j < 4; ++j){
      int m = ml0 + j;
      unsigned int lo = pk2(r[it*4+0][j], r[it*4+1][j]);
      unsigned int hi = pk2(r[it*4+2][j], r[it*4+3][j]);
      int off = m * 512 + ((c0 * 2) ^ swz8(m));
      unsigned long long v = (unsigned long long)lo | ((unsigned long long)hi << 32);
      *(unsigned long long*)((char*)xT + off) = v;
    }
  }
}

// ---------------- kernel 0: weights -> bf16 fragment-order pack -------------
// wkvf: [h][ot 0..3][kk 0..7][lane 0..63] x 16B ; ot 0,1 = Wk rows, 2,3 = Wv.
// wqf : [h][ot 0..1][kk 0..7][lane 0..63] x 16B.
// Hot-loop load becomes frag_base + lane*16 (fully coalesced).
__global__ void wconv(const float* __restrict__ wq, const float* __restrict__ wk,
                      const float* __restrict__ wv,
                      unsigned short* __restrict__ wkvf, unsigned short* __restrict__ wqf){
  int t = blockIdx.x * 256 + threadIdx.x;   // 24576 threads
  if (t < 16384){                           // wkvf frag slots
    int lane = t & 63, kk = (t >> 6) & 7, ot = (t >> 9) & 3, h = t >> 11;
    int l15 = lane & 15, hi = lane >> 4;
    const float* src = (ot < 2) ? (wk + (size_t)(h * 32 + ot * 16 + l15) * 256)
                                : (wv + (size_t)(h * 32 + (ot - 2) * 16 + l15) * 256);
    src += kk * 32 + hi * 8;
    unsigned short* dst = wkvf + (size_t)t * 8;
    #pragma unroll
    for (int j = 0; j < 8; ++j) dst[j] = f2bf(src[j]);
  } else if (t < 24576){                    // wqf frag slots
    int u = t - 16384;
    int lane = u & 63, kk = (u >> 6) & 7, ot = (u >> 9) & 1, h = u >> 10;
    int l15 = lane & 15, hi = lane >> 4;
    const float* src = wq + (size_t)(h * 32 + ot * 16 + l15) * 256 + kk * 32 + hi * 8;
    unsigned short* dst = wqf + (size_t)u * 8;
    #pragma unroll
    for (int j = 0; j < 8; ++j) dst[j] = f2bf(src[j]);
  }
}

// ---------------- kernel 0b: x -> pre-swizzled bf16 tile images -------------
// ximg: [b][64 tiles][16384 ushort] ; tile = x^T [64 m][256 c] swizzled image
__global__ void __launch_bounds__(512) xcvt(const float* __restrict__ x,
                                            unsigned short* __restrict__ ximg){
  __shared__ __align__(16) unsigned short xT[16384];
  const int tid = threadIdx.x;
  const int ch = blockIdx.x, b = blockIdx.y;
  const float* xb = x + (size_t)b * (256 * 4096);
  for (int sub = 0; sub < 2; ++sub){
    int m0 = ch * 128 + sub * 64;
    float4v rs[8];
    stage_load(xb, m0, tid, rs);
    if (sub) __syncthreads();          // previous tile's dump finished
    stage_write(xT, tid, rs);
    __syncthreads();
    unsigned short* dst = ximg + ((size_t)b * 64 + (m0 >> 6)) * 16384;
    #pragma unroll
    for (int i = 0; i < 4; ++i){
      u32x4 v = *(const u32x4*)((const char*)xT + tid * 16 + i * 8192);
      *(u32x4*)((char*)dst + tid * 16 + i * 8192) = v;
    }
  }
}

// --- one 64-m subtile: K/V projection + fold into KV/ksum accumulators ------
DEVI void compute_sub(const unsigned short* __restrict__ xT,
                      const unsigned short* __restrict__ wkvf,
                      int w, int l15, int hi, int lane,
                      f32x4 (&kvacc)[2][2], f32x4 (&ksacc)[2], u32x4 ones){
  f32x4 acc[4][4];                         // [nt m-tile][ot: 0,1=K, 2,3=V]
  #pragma unroll
  for (int a1 = 0; a1 < 4; ++a1)
    #pragma unroll
    for (int a2 = 0; a2 < 4; ++a2) acc[a1][a2] = f32x4{0.f,0.f,0.f,0.f};

  for (int kk = 0; kk < 8; ++kk){
    u32x4 xf[4];
    #pragma unroll
    for (int nt = 0; nt < 4; ++nt){
      int m = nt * 16 + l15;
      xf[nt] = *(const u32x4*)((const char*)xT + m * 512 + ((kk * 64 + hi * 16) ^ swz8(m)));
    }
    #pragma unroll
    for (int ot = 0; ot < 4; ++ot){
      // fragment-order weight load: fully coalesced (lane*16)
      u32x4 wf = *(const u32x4*)(wkvf + ((((size_t)w * 4 + ot) * 8 + kk) * 64 + lane) * 8);
      #pragma unroll
      for (int nt = 0; nt < 4; ++nt) acc[nt][ot] = mfma16(xf[nt], wf, acc[nt][ot]);
    }
  }
  // lane holds c = l15 (per o-tile), 8 m-values; pack bf16 frags in-register.
  #pragma unroll
  for (int g = 0; g < 2; ++g){
    u32x4 kf[2], vf[2];
    #pragma unroll
    for (int t2 = 0; t2 < 2; ++t2){
      kf[t2][0] = pk2(feat(acc[2*g][t2][0]),   feat(acc[2*g][t2][1]));
      kf[t2][1] = pk2(feat(acc[2*g][t2][2]),   feat(acc[2*g][t2][3]));
      kf[t2][2] = pk2(feat(acc[2*g+1][t2][0]), feat(acc[2*g+1][t2][1]));
      kf[t2][3] = pk2(feat(acc[2*g+1][t2][2]), feat(acc[2*g+1][t2][3]));
      vf[t2][0] = pk2(acc[2*g][t2+2][0],   acc[2*g][t2+2][1]);
      vf[t2][1] = pk2(acc[2*g][t2+2][2],   acc[2*g][t2+2][3]);
      vf[t2][2] = pk2(acc[2*g+1][t2+2][0], acc[2*g+1][t2+2][1]);
      vf[t2][3] = pk2(acc[2*g+1][t2+2][2], acc[2*g+1][t2+2][3]);
    }
    #pragma unroll
    for (int ct = 0; ct < 2; ++ct){
      #pragma unroll
      for (int dt = 0; dt < 2; ++dt)
        kvacc[ct][dt] = mfma16(kf[ct], vf[dt], kvacc[ct][dt]);
      ksacc[ct] = mfma16(kf[ct], ones, ksacc[ct]);
    }
  }
}

// ---------------- kernel 1: K/V projection + per-chunk KV & ksum partials ----
// grid (32 chunks, 16 batches), 512 threads = 8 waves = 8 heads; 2 subtiles.
__global__ void __launch_bounds__(512) k_kv(const unsigned short* __restrict__ ximg,
        const unsigned short* __restrict__ wkvf,
        float* __restrict__ kvp, float* __restrict__ ksp){
  __shared__ __align__(16) unsigned short xT[2][16384];   // 64KB double-buffer
  const int tid = threadIdx.x, lane = tid & 63, w = tid >> 6;
  const int l15 = lane & 15, hi = lane >> 4;
  const int ch = blockIdx.x, b = blockIdx.y;
  const char* src = (const char*)(ximg + ((size_t)b * 64 + ch * 2) * 16384);

  f32x4 kvacc[2][2];
  f32x4 ksacc[2];
  #pragma unroll
  for (int i = 0; i < 2; ++i){
    ksacc[i] = f32x4{0.f,0.f,0.f,0.f};
    #pragma unroll
    for (int j = 0; j < 2; ++j) kvacc[i][j] = f32x4{0.f,0.f,0.f,0.f};
  }
  u32x4 ones = {0u,0u,0u,0u};               // B-frag: column d=0 all-ones -> ksum
  if (l15 == 0){ ones[0] = ones[1] = ones[2] = ones[3] = 0x3f803f80u; }

  stage_tile(src, xT[0], w, lane);
  __syncthreads();                                   // t0 ready
  stage_tile(src + 32768, xT[1], w, lane);           // issue t1 async
  compute_sub(xT[0], wkvf, w, l15, hi, lane, kvacc, ksacc, ones);
  __syncthreads();                                   // t1 drained
  compute_sub(xT[1], wkvf, w, l15, hi, lane, kvacc, ksacc, ones);

  // partial stores: kvp [b][32 ch][8 h][32 c][32 d], ksp [b][32 ch][8 h][32 c]
  size_t base = (((size_t)b * 32 + ch) * 8 + w) * 1024;
  #pragma unroll
  for (int ct = 0; ct < 2; ++ct){
    #pragma unroll
    for (int dt = 0; dt < 2; ++dt){
      #pragma unroll
      for (int r = 0; r < 4; ++r){
        int c = ct * 16 + hi * 4 + r, d = dt * 16 + l15;
        kvp[base + c * 32 + d] = kvacc[ct][dt][r];
      }
    }
  }
  if (l15 == 0){
    size_t kb = (((size_t)b * 32 + ch) * 8 + w) * 32;
    #pragma unroll
    for (int ct = 0; ct < 2; ++ct)
      #pragma unroll
      for (int r = 0; r < 4; ++r) ksp[kb + ct * 16 + hi * 4 + r] = ksacc[ct][r];
  }
}

// ---------------- kernel 2: reduce partials -> KV^T bf16 [b][h][d][pos(c)], ksum bf16
// slot permutation matching k_q's in-register q frag: pos(c) = ((c>>2)&3)*8 + (c>>4)*4 + (c&3)
__global__ void k_red(const float* __restrict__ kvp, const float* __restrict__ ksp,
                      unsigned short* __restrict__ kvt, unsigned short* __restrict__ ksb){
  int t = blockIdx.x * 256 + threadIdx.x;   // 32768 threads: (b,h,c,dq)
  int dq = t & 7;            // d-quad
  int c  = (t >> 3) & 31;
  int h  = (t >> 8) & 7;
  int b  = t >> 11;
  float4v s = {0.f,0.f,0.f,0.f};
  for (int c2 = 0; c2 < 32; ++c2){
    const float* p = kvp + ((((size_t)b * 32 + c2) * 8 + h) * 1024) + c * 32 + dq * 4;
    float4v r = *(const float4v*)p;
    s.x += r.x; s.y += r.y; s.z += r.z; s.w += r.w;
  }
  int pos = ((c >> 2) & 3) * 8 + ((c >> 4) << 2) + (c & 3);
  unsigned short* q = kvt + ((size_t)b * 8 + h) * 1024;
  q[(dq * 4 + 0) * 32 + pos] = f2bf(s.x);
  q[(dq * 4 + 1) * 32 + pos] = f2bf(s.y);
  q[(dq * 4 + 2) * 32 + pos] = f2bf(s.z);
  q[(dq * 4 + 3) * 32 + pos] = f2bf(s.w);
  if (dq == 0){
    float ks = 0.f;
    for (int c2 = 0; c2 < 32; ++c2)
      ks += ksp[(((size_t)b * 32 + c2) * 8 + h) * 32 + c];
    ksb[((size_t)b * 8 + h) * 32 + pos] = f2bf(ks);
  }
}

// --- one 64-m subtile of k_q: Q projection + out = KV^T q / denom -----------
DEVI void q_sub(const unsigned short* __restrict__ xT,
                const unsigned short* __restrict__ wqf,
                u32x4 afkv0, u32x4 afkv1, u32x4 afd,
                int w, int l15, int hi, int lane, float* __restrict__ ob){
  f32x4 qa[2][4];                           // [ot = c-tile][nt = m-tile]
  #pragma unroll
  for (int a1 = 0; a1 < 2; ++a1)
    #pragma unroll
    for (int a2 = 0; a2 < 4; ++a2) qa[a1][a2] = f32x4{0.f,0.f,0.f,0.f};

  for (int kk = 0; kk < 8; ++kk){
    u32x4 xf[4];
    #pragma unroll
    for (int nt = 0; nt < 4; ++nt){
      int m = nt * 16 + l15;
      xf[nt] = *(const u32x4*)((const char*)xT + m * 512 + ((kk * 64 + hi * 16) ^ swz8(m)));
    }
    #pragma unroll
    for (int ot = 0; ot < 2; ++ot){
      // fragment-order weight load: fully coalesced (lane*16)
      u32x4 wf = *(const u32x4*)(wqf + ((((size_t)w * 2 + ot) * 8 + kk) * 64 + lane) * 8);
      #pragma unroll
      for (int nt = 0; nt < 4; ++nt) qa[ot][nt] = mfma16(wf, xf[nt], qa[ot][nt]);
    }
  }

  #pragma unroll
  for (int nt = 0; nt < 4; ++nt){
    // q B-frag in-register: lane l15 = m, slots = c (ot0 r0..3, ot1 r0..3)
    u32x4 bq;
    bq[0] = pk2(feat(qa[0][nt][0]), feat(qa[0][nt][1]));
    bq[1] = pk2(feat(qa[0][nt][2]), feat(qa[0][nt][3]));
    bq[2] = pk2(feat(qa[1][nt][0]), feat(qa[1][nt][1]));
    bq[3] = pk2(feat(qa[1][nt][2]), feat(qa[1][nt][3]));

    f32x4 o0 = {0.f,0.f,0.f,0.f}, o1 = {0.f,0.f,0.f,0.f}, dn = {0.f,0.f,0.f,0.f};
    o0 = mfma16(afkv0, bq, o0);
    o1 = mfma16(afkv1, bq, o1);
    dn = mfma16(afd, bq, dn);
    float dv = __shfl(dn[0], l15, 64);       // lanes hi==0 hold denom[m] in reg0
    float inv = 1.0f / fmaxf(dv, 1e-6f);
    #pragma unroll
    for (int r = 0; r < 4; ++r){
      ob[(size_t)(hi * 4 + r) * 4096 + nt * 16 + l15]      = o0[r] * inv;
      ob[(size_t)(16 + hi * 4 + r) * 4096 + nt * 16 + l15] = o1[r] * inv;
    }
  }
}

// ---------------- kernel 3: Q projection + apply KV -------------------------
// grid (32 chunks, 16 batches), 512 threads = 8 waves = 8 heads; 2 subtiles.
__global__ void __launch_bounds__(512) k_q(const unsigned short* __restrict__ ximg,
        const unsigned short* __restrict__ wqf,
        const unsigned short* __restrict__ kvt,
        const unsigned short* __restrict__ ksb,
        float* __restrict__ out){
  __shared__ __align__(16) unsigned short xT[2][16384];   // 64KB double-buffer
  const int tid = threadIdx.x, lane = tid & 63, w = tid >> 6;
  const int l15 = lane & 15, hi = lane >> 4;
  const int ch = blockIdx.x, b = blockIdx.y;
  const char* src = (const char*)(ximg + ((size_t)b * 64 + ch * 2) * 16384);

  // KV^T / ksum frags (slot-permuted storage from k_red matches q packing)
  size_t kvbase = ((size_t)b * 8 + w) * 1024;
  u32x4 afkv0 = *(const u32x4*)(kvt + kvbase + (size_t)l15 * 32 + hi * 8);        // d = l15
  u32x4 afkv1 = *(const u32x4*)(kvt + kvbase + (size_t)(16 + l15) * 32 + hi * 8); // d = 16+l15
  u32x4 afd = {0u,0u,0u,0u};                 // row0 = ksum -> D[0][m] = denom
  if (l15 == 0) afd = *(const u32x4*)(ksb + ((size_t)b * 8 + w) * 32 + hi * 8);

  stage_tile(src, xT[0], w, lane);
  __syncthreads();                                   // t0 ready
  stage_tile(src + 32768, xT[1], w, lane);           // issue t1 async

  float* ob = out + ((size_t)b * 256 + w * 32) * 4096 + ch * 128;
  q_sub(xT[0], wqf, afkv0, afkv1, afd, w, l15, hi, lane, ob);
  __syncthreads();                                   // t1 drained
  q_sub(xT[1], wqf, afkv0, afkv1, afd, w, l15, hi, lane, ob + 64);
}

extern "C" void kernel_launch(void* const* d_in, const int* in_sizes, int n_in,
                              void* d_out, int out_size, void* d_ws, size_t ws_size,
                              hipStream_t stream) {
  const float* x  = (const float*)d_in[0];
  const float* wq = (const float*)d_in[1];
  const float* wk = (const float*)d_in[2];
  const float* wv = (const float*)d_in[3];
  float* out = (float*)d_out;
  char* ws = (char*)d_ws;

  // ws layout (bytes): total ~49.5 MB
  unsigned short* wkvf = (unsigned short*)(ws);                  // 262144
  unsigned short* wqf  = (unsigned short*)(ws + 262144);         // 131072
  unsigned short* kvt  = (unsigned short*)(ws + 393216);         // 262144
  unsigned short* ksb  = (unsigned short*)(ws + 655360);         // 8192
  float* kvp = (float*)(ws + 1048576);                           // 16777216
  float* ksp = (float*)(ws + 17825792);                          // 524288
  unsigned short* ximg = (unsigned short*)(ws + 18350080);       // 33554432

  hipLaunchKernelGGL(wconv, dim3(96), dim3(256), 0, stream, wq, wk, wv, wkvf, wqf);
  hipLaunchKernelGGL(xcvt,  dim3(32, 16), dim3(512), 0, stream, x, ximg);
  hipLaunchKernelGGL(k_kv,  dim3(32, 16), dim3(512), 0, stream, ximg, wkvf, kvp, ksp);
  hipLaunchKernelGGL(k_red, dim3(128), dim3(256), 0, stream, kvp, ksp, kvt, ksb);
  hipLaunchKernelGGL(k_q,   dim3(32, 16), dim3(512), 0, stream, ximg, wqf, kvt, ksb, out);
}

// Round 7
// 81.043 us; speedup vs baseline: 1.2381x; 1.0580x over previous
//
#include <hip/hip_runtime.h>
#include <hip/hip_bf16.h>

// MultiHeadLinearAttention2D on MI355X (gfx950), bf16-MFMA implementation.
// B=16, C_in=C_out=256, H=W=64 (M=4096), heads=8, dh=32, scale=1/sqrt(32).
//
// Round-7: recover from the failed cooperative launch (R6: co-residency
// rejection suspected -> kernel never ran). Non-cooperative fusion instead:
//  - xcvt is gone. k_kv reg-stages x directly (fp32->bf16+swizzle inline,
//    double-buffered, issue-early/write-late) and dumps the finished bf16
//    tile images to ximg as a side product for k_q.
//  - x is read from HBM exactly once; net -32 MB traffic and one less
//    serialized dispatch vs R5.
//  - k_q / k_red / wconv unchanged from R5 (frag-order weights).

typedef __attribute__((ext_vector_type(8))) short bf16x8;
typedef __attribute__((ext_vector_type(4))) float f32x4;
typedef __attribute__((ext_vector_type(4))) unsigned int u32x4;
typedef __attribute__((ext_vector_type(4))) float float4v;

#define DEVI static __device__ __forceinline__

DEVI unsigned short f2bf(float f){
  unsigned int u = __builtin_bit_cast(unsigned int, f);
  u = (u + 0x7fffu + ((u >> 16) & 1u)) >> 16;   // RNE truncate to bf16
  return (unsigned short)u;
}
DEVI unsigned int pk2(float a, float b){
  return (unsigned int)f2bf(a) | ((unsigned int)f2bf(b) << 16);
}
DEVI float feat(float p){   // (elu(p)+1) * 1/sqrt(32)
  return (p > 0.f ? p + 1.f : __expf(p)) * 0.17677669529663687f;
}

DEVI f32x4 mfma16(u32x4 a, u32x4 b, f32x4 c){
  return __builtin_amdgcn_mfma_f32_16x16x32_bf16(
      __builtin_bit_cast(bf16x8, a), __builtin_bit_cast(bf16x8, b), c, 0, 0, 0);
}

// byte-XOR swizzle (G4) for 512B rows of the x^T tile image
DEVI int swz8(int m){ return ((m ^ (m >> 3)) & 7) << 4; }

// async global->LDS, 16B per lane; LDS base must be wave-uniform
typedef __attribute__((address_space(3))) unsigned int as3_u32;
typedef __attribute__((address_space(1))) const unsigned int as1_u32;
DEVI void gload16(const void* g, void* l){
  __builtin_amdgcn_global_load_lds((as1_u32*)g, (as3_u32*)l, 16, 0, 0);
}
// stage one 32KB pre-swizzled tile image (global -> LDS), async
DEVI void stage_tile(const char* src, void* buf, int w, int lane){
  #pragma unroll
  for (int i = 0; i < 4; ++i){
    int ub = w * 1024 + i * 8192;               // wave-uniform LDS base
    gload16(src + ub + lane * 16, (char*)buf + ub);
  }
}

// --- fp32 x-tile [256 c][64 m] -> registers -> swizzled bf16 LDS image ------
DEVI void stage_load(const float* __restrict__ xb, int m0, int tid, float4v* r){
  #pragma unroll
  for (int it = 0; it < 2; ++it){
    int cq = (tid >> 4) + it * 32;     // 0..63 -> c0 = 4*cq
    int mq = tid & 15;                 // 0..15 -> ml0 = 4*mq
    const float* p = xb + (size_t)(cq * 4) * 4096 + m0 + mq * 4;
    r[it*4+0] = *(const float4v*)(p);
    r[it*4+1] = *(const float4v*)(p + 4096);
    r[it*4+2] = *(const float4v*)(p + 8192);
    r[it*4+3] = *(const float4v*)(p + 12288);
  }
}
DEVI void stage_write(unsigned short* xT, int tid, const float4v* r){
  #pragma unroll
  for (int it = 0; it < 2; ++it){
    int cq = (tid >> 4) + it * 32;
    int mq = tid & 15;
    int c0 = cq * 4, ml0 = mq * 4;
    #pragma unroll
    for (int j = 0; j < 4; ++j){
      int m = ml0 + j;
      unsigned int lo = pk2(r[it*4+0][j], r[it*4+1][j]);
      unsigned int hi = pk2(r[it*4+2][j], r[it*4+3][j]);
      int off = m * 512 + ((c0 * 2) ^ swz8(m));
      unsigned long long v = (unsigned long long)lo | ((unsigned long long)hi << 32);
      *(unsigned long long*)((char*)xT + off) = v;
    }
  }
}
// dump one finished 32KB LDS tile image to global (coalesced dwordx4)
DEVI void dump_tile(const unsigned short* xT, unsigned short* dst, int tid){
  #pragma unroll
  for (int i = 0; i < 4; ++i){
    u32x4 v = *(const u32x4*)((const char*)xT + tid * 16 + i * 8192);
    *(u32x4*)((char*)dst + tid * 16 + i * 8192) = v;
  }
}

// ---------------- kernel 0: weights -> bf16 fragment-order pack -------------
// wkvf: [h][ot 0..3][kk 0..7][lane 0..63] x 16B ; ot 0,1 = Wk rows, 2,3 = Wv.
// wqf : [h][ot 0..1][kk 0..7][lane 0..63] x 16B.
__global__ void wconv(const float* __restrict__ wq, const float* __restrict__ wk,
                      const float* __restrict__ wv,
                      unsigned short* __restrict__ wkvf, unsigned short* __restrict__ wqf){
  int t = blockIdx.x * 256 + threadIdx.x;   // 24576 threads
  if (t < 16384){                           // wkvf frag slots
    int lane = t & 63, kk = (t >> 6) & 7, ot = (t >> 9) & 3, h = t >> 11;
    int l15 = lane & 15, hi = lane >> 4;
    const float* src = (ot < 2) ? (wk + (size_t)(h * 32 + ot * 16 + l15) * 256)
                                : (wv + (size_t)(h * 32 + (ot - 2) * 16 + l15) * 256);
    src += kk * 32 + hi * 8;
    unsigned short* dst = wkvf + (size_t)t * 8;
    #pragma unroll
    for (int j = 0; j < 8; ++j) dst[j] = f2bf(src[j]);
  } else if (t < 24576){                    // wqf frag slots
    int u = t - 16384;
    int lane = u & 63, kk = (u >> 6) & 7, ot = (u >> 9) & 1, h = u >> 10;
    int l15 = lane & 15, hi = lane >> 4;
    const float* src = wq + (size_t)(h * 32 + ot * 16 + l15) * 256 + kk * 32 + hi * 8;
    unsigned short* dst = wqf + (size_t)u * 8;
    #pragma unroll
    for (int j = 0; j < 8; ++j) dst[j] = f2bf(src[j]);
  }
}

// --- one 64-m subtile: K/V projection + fold into KV/ksum accumulators ------
DEVI void compute_sub(const unsigned short* __restrict__ xT,
                      const unsigned short* __restrict__ wkvf,
                      int w, int l15, int hi, int lane,
                      f32x4 (&kvacc)[2][2], f32x4 (&ksacc)[2], u32x4 ones){
  f32x4 acc[4][4];                         // [nt m-tile][ot: 0,1=K, 2,3=V]
  #pragma unroll
  for (int a1 = 0; a1 < 4; ++a1)
    #pragma unroll
    for (int a2 = 0; a2 < 4; ++a2) acc[a1][a2] = f32x4{0.f,0.f,0.f,0.f};

  for (int kk = 0; kk < 8; ++kk){
    u32x4 xf[4];
    #pragma unroll
    for (int nt = 0; nt < 4; ++nt){
      int m = nt * 16 + l15;
      xf[nt] = *(const u32x4*)((const char*)xT + m * 512 + ((kk * 64 + hi * 16) ^ swz8(m)));
    }
    #pragma unroll
    for (int ot = 0; ot < 4; ++ot){
      // fragment-order weight load: fully coalesced (lane*16), L2-resident
      u32x4 wf = *(const u32x4*)(wkvf + ((((size_t)w * 4 + ot) * 8 + kk) * 64 + lane) * 8);
      #pragma unroll
      for (int nt = 0; nt < 4; ++nt) acc[nt][ot] = mfma16(xf[nt], wf, acc[nt][ot]);
    }
  }
  // lane holds c = l15 (per o-tile), 8 m-values; pack bf16 frags in-register.
  #pragma unroll
  for (int g = 0; g < 2; ++g){
    u32x4 kf[2], vf[2];
    #pragma unroll
    for (int t2 = 0; t2 < 2; ++t2){
      kf[t2][0] = pk2(feat(acc[2*g][t2][0]),   feat(acc[2*g][t2][1]));
      kf[t2][1] = pk2(feat(acc[2*g][t2][2]),   feat(acc[2*g][t2][3]));
      kf[t2][2] = pk2(feat(acc[2*g+1][t2][0]), feat(acc[2*g+1][t2][1]));
      kf[t2][3] = pk2(feat(acc[2*g+1][t2][2]), feat(acc[2*g+1][t2][3]));
      vf[t2][0] = pk2(acc[2*g][t2+2][0],   acc[2*g][t2+2][1]);
      vf[t2][1] = pk2(acc[2*g][t2+2][2],   acc[2*g][t2+2][3]);
      vf[t2][2] = pk2(acc[2*g+1][t2+2][0], acc[2*g+1][t2+2][1]);
      vf[t2][3] = pk2(acc[2*g+1][t2+2][2], acc[2*g+1][t2+2][3]);
    }
    #pragma unroll
    for (int ct = 0; ct < 2; ++ct){
      #pragma unroll
      for (int dt = 0; dt < 2; ++dt)
        kvacc[ct][dt] = mfma16(kf[ct], vf[dt], kvacc[ct][dt]);
      ksacc[ct] = mfma16(kf[ct], ones, ksacc[ct]);
    }
  }
}

// ---------------- kernel 1: stage x once -> K/V partials + ximg dump --------
// grid (32 chunks, 16 batches), 512 threads = 8 waves = 8 heads; 2 subtiles.
__global__ void __launch_bounds__(512) k_kv(const float* __restrict__ x,
        const unsigned short* __restrict__ wkvf,
        float* __restrict__ kvp, float* __restrict__ ksp,
        unsigned short* __restrict__ ximg){
  __shared__ __align__(16) unsigned short xT[2][16384];   // 64KB double-buffer
  const int tid = threadIdx.x, lane = tid & 63, w = tid >> 6;
  const int l15 = lane & 15, hi = lane >> 4;
  const int ch = blockIdx.x, b = blockIdx.y;
  const float* xb = x + (size_t)b * (256 * 4096);
  unsigned short* img = ximg + ((size_t)b * 64 + ch * 2) * 16384;

  f32x4 kvacc[2][2];
  f32x4 ksacc[2];
  #pragma unroll
  for (int i = 0; i < 2; ++i){
    ksacc[i] = f32x4{0.f,0.f,0.f,0.f};
    #pragma unroll
    for (int j = 0; j < 2; ++j) kvacc[i][j] = f32x4{0.f,0.f,0.f,0.f};
  }
  u32x4 ones = {0u,0u,0u,0u};               // B-frag: column d=0 all-ones -> ksum
  if (l15 == 0){ ones[0] = ones[1] = ones[2] = ones[3] = 0x3f803f80u; }

  float4v rs[8];
  stage_load(xb, ch * 128, tid, rs);
  stage_write(xT[0], tid, rs);
  __syncthreads();
  stage_load(xb, ch * 128 + 64, tid, rs);               // issue t1 early
  compute_sub(xT[0], wkvf, w, l15, hi, lane, kvacc, ksacc, ones);
  dump_tile(xT[0], img, tid);                           // side-product for k_q
  stage_write(xT[1], tid, rs);                          // write late
  __syncthreads();
  compute_sub(xT[1], wkvf, w, l15, hi, lane, kvacc, ksacc, ones);
  dump_tile(xT[1], img + 16384, tid);

  // partial stores: kvp [b][32 ch][8 h][32 c][32 d], ksp [b][32 ch][8 h][32 c]
  size_t base = (((size_t)b * 32 + ch) * 8 + w) * 1024;
  #pragma unroll
  for (int ct = 0; ct < 2; ++ct){
    #pragma unroll
    for (int dt = 0; dt < 2; ++dt){
      #pragma unroll
      for (int r = 0; r < 4; ++r){
        int c = ct * 16 + hi * 4 + r, d = dt * 16 + l15;
        kvp[base + c * 32 + d] = kvacc[ct][dt][r];
      }
    }
  }
  if (l15 == 0){
    size_t kb = (((size_t)b * 32 + ch) * 8 + w) * 32;
    #pragma unroll
    for (int ct = 0; ct < 2; ++ct)
      #pragma unroll
      for (int r = 0; r < 4; ++r) ksp[kb + ct * 16 + hi * 4 + r] = ksacc[ct][r];
  }
}

// ---------------- kernel 2: reduce partials -> KV^T bf16 [b][h][d][pos(c)], ksum bf16
// slot permutation matching k_q's in-register q frag: pos(c) = ((c>>2)&3)*8 + (c>>4)*4 + (c&3)
__global__ void k_red(const float* __restrict__ kvp, const float* __restrict__ ksp,
                      unsigned short* __restrict__ kvt, unsigned short* __restrict__ ksb){
  int t = blockIdx.x * 256 + threadIdx.x;   // 32768 threads: (b,h,c,dq)
  int dq = t & 7;            // d-quad
  int c  = (t >> 3) & 31;
  int h  = (t >> 8) & 7;
  int b  = t >> 11;
  float4v s = {0.f,0.f,0.f,0.f};
  for (int c2 = 0; c2 < 32; ++c2){
    const float* p = kvp + ((((size_t)b * 32 + c2) * 8 + h) * 1024) + c * 32 + dq * 4;
    float4v r = *(const float4v*)p;
    s.x += r.x; s.y += r.y; s.z += r.z; s.w += r.w;
  }
  int pos = ((c >> 2) & 3) * 8 + ((c >> 4) << 2) + (c & 3);
  unsigned short* q = kvt + ((size_t)b * 8 + h) * 1024;
  q[(dq * 4 + 0) * 32 + pos] = f2bf(s.x);
  q[(dq * 4 + 1) * 32 + pos] = f2bf(s.y);
  q[(dq * 4 + 2) * 32 + pos] = f2bf(s.z);
  q[(dq * 4 + 3) * 32 + pos] = f2bf(s.w);
  if (dq == 0){
    float ks = 0.f;
    for (int c2 = 0; c2 < 32; ++c2)
      ks += ksp[(((size_t)b * 32 + c2) * 8 + h) * 32 + c];
    ksb[((size_t)b * 8 + h) * 32 + pos] = f2bf(ks);
  }
}

// --- one 64-m subtile of k_q: Q projection + out = KV^T q / denom -----------
DEVI void q_sub(const unsigned short* __restrict__ xT,
                const unsigned short* __restrict__ wqf,
                u32x4 afkv0, u32x4 afkv1, u32x4 afd,
                int w, int l15, int hi, int lane, float* __restrict__ ob){
  f32x4 qa[2][4];                           // [ot = c-tile][nt = m-tile]
  #pragma unroll
  for (int a1 = 0; a1 < 2; ++a1)
    #pragma unroll
    for (int a2 = 0; a2 < 4; ++a2) qa[a1][a2] = f32x4{0.f,0.f,0.f,0.f};

  for (int kk = 0; kk < 8; ++kk){
    u32x4 xf[4];
    #pragma unroll
    for (int nt = 0; nt < 4; ++nt){
      int m = nt * 16 + l15;
      xf[nt] = *(const u32x4*)((const char*)xT + m * 512 + ((kk * 64 + hi * 16) ^ swz8(m)));
    }
    #pragma unroll
    for (int ot = 0; ot < 2; ++ot){
      u32x4 wf = *(const u32x4*)(wqf + ((((size_t)w * 2 + ot) * 8 + kk) * 64 + lane) * 8);
      #pragma unroll
      for (int nt = 0; nt < 4; ++nt) qa[ot][nt] = mfma16(wf, xf[nt], qa[ot][nt]);
    }
  }

  #pragma unroll
  for (int nt = 0; nt < 4; ++nt){
    // q B-frag in-register: lane l15 = m, slots = c (ot0 r0..3, ot1 r0..3)
    u32x4 bq;
    bq[0] = pk2(feat(qa[0][nt][0]), feat(qa[0][nt][1]));
    bq[1] = pk2(feat(qa[0][nt][2]), feat(qa[0][nt][3]));
    bq[2] = pk2(feat(qa[1][nt][0]), feat(qa[1][nt][1]));
    bq[3] = pk2(feat(qa[1][nt][2]), feat(qa[1][nt][3]));

    f32x4 o0 = {0.f,0.f,0.f,0.f}, o1 = {0.f,0.f,0.f,0.f}, dn = {0.f,0.f,0.f,0.f};
    o0 = mfma16(afkv0, bq, o0);
    o1 = mfma16(afkv1, bq, o1);
    dn = mfma16(afd, bq, dn);
    float dv = __shfl(dn[0], l15, 64);       // lanes hi==0 hold denom[m] in reg0
    float inv = 1.0f / fmaxf(dv, 1e-6f);
    #pragma unroll
    for (int r = 0; r < 4; ++r){
      ob[(size_t)(hi * 4 + r) * 4096 + nt * 16 + l15]      = o0[r] * inv;
      ob[(size_t)(16 + hi * 4 + r) * 4096 + nt * 16 + l15] = o1[r] * inv;
    }
  }
}

// ---------------- kernel 3: Q projection + apply KV -------------------------
// grid (32 chunks, 16 batches), 512 threads = 8 waves = 8 heads; 2 subtiles.
__global__ void __launch_bounds__(512) k_q(const unsigned short* __restrict__ ximg,
        const unsigned short* __restrict__ wqf,
        const unsigned short* __restrict__ kvt,
        const unsigned short* __restrict__ ksb,
        float* __restrict__ out){
  __shared__ __align__(16) unsigned short xT[2][16384];   // 64KB double-buffer
  const int tid = threadIdx.x, lane = tid & 63, w = tid >> 6;
  const int l15 = lane & 15, hi = lane >> 4;
  const int ch = blockIdx.x, b = blockIdx.y;
  const char* src = (const char*)(ximg + ((size_t)b * 64 + ch * 2) * 16384);

  // KV^T / ksum frags (slot-permuted storage from k_red matches q packing)
  size_t kvbase = ((size_t)b * 8 + w) * 1024;
  u32x4 afkv0 = *(const u32x4*)(kvt + kvbase + (size_t)l15 * 32 + hi * 8);        // d = l15
  u32x4 afkv1 = *(const u32x4*)(kvt + kvbase + (size_t)(16 + l15) * 32 + hi * 8); // d = 16+l15
  u32x4 afd = {0u,0u,0u,0u};                 // row0 = ksum -> D[0][m] = denom
  if (l15 == 0) afd = *(const u32x4*)(ksb + ((size_t)b * 8 + w) * 32 + hi * 8);

  stage_tile(src, xT[0], w, lane);
  __syncthreads();                                   // t0 ready
  stage_tile(src + 32768, xT[1], w, lane);           // issue t1 async

  float* ob = out + ((size_t)b * 256 + w * 32) * 4096 + ch * 128;
  q_sub(xT[0], wqf, afkv0, afkv1, afd, w, l15, hi, lane, ob);
  __syncthreads();                                   // t1 drained
  q_sub(xT[1], wqf, afkv0, afkv1, afd, w, l15, hi, lane, ob + 64);
}

extern "C" void kernel_launch(void* const* d_in, const int* in_sizes, int n_in,
                              void* d_out, int out_size, void* d_ws, size_t ws_size,
                              hipStream_t stream) {
  const float* x  = (const float*)d_in[0];
  const float* wq = (const float*)d_in[1];
  const float* wk = (const float*)d_in[2];
  const float* wv = (const float*)d_in[3];
  float* out = (float*)d_out;
  char* ws = (char*)d_ws;

  // ws layout (bytes): total ~49.5 MB
  unsigned short* wkvf = (unsigned short*)(ws);                  // 262144
  unsigned short* wqf  = (unsigned short*)(ws + 262144);         // 131072
  unsigned short* kvt  = (unsigned short*)(ws + 393216);         // 262144
  unsigned short* ksb  = (unsigned short*)(ws + 655360);         // 8192
  float* kvp = (float*)(ws + 1048576);                           // 16777216
  float* ksp = (float*)(ws + 17825792);                          // 524288
  unsigned short* ximg = (unsigned short*)(ws + 18350080);       // 33554432

  hipLaunchKernelGGL(wconv, dim3(96), dim3(256), 0, stream, wq, wk, wv, wkvf, wqf);
  hipLaunchKernelGGL(k_kv,  dim3(32, 16), dim3(512), 0, stream, x, wkvf, kvp, ksp, ximg);
  hipLaunchKernelGGL(k_red, dim3(128), dim3(256), 0, stream, kvp, ksp, kvt, ksb);
  hipLaunchKernelGGL(k_q,   dim3(32, 16), dim3(512), 0, stream, ximg, wqf, kvt, ksb, out);
}